// Round 3
// baseline (786.677 us; speedup 1.0000x reference)
//
#include <hip/hip_runtime.h>
#include <hip/hip_bf16.h>

// MoE Router (Switch): logits = x@W + b; top-3 one-hot mask; softmax probs;
// importance = load = column-sum of probs.
// x: [N=32768, D=2048] f32, W: [D, E=64] f32, b: [E] f32.
// out = [mask (N*E) | prob (N*E) | importance (E) | load (E)]  (f32)
//
// Design: lane = expert (E == wavefront size 64). Each wave computes TM=8 rows.
// W staged through LDS in BK=64 chunks; x read through the scalar path
// (wave-uniform row base via readfirstlane -> s_load).
//
// R2 fix: the LDS staging only copied 1024 of 4096 floats per chunk
// (256 thr x float4 = 4 KB, chunk is 16 KB) — kk>=16 read uninitialized
// LDS. Mask/prob "passed" earlier only because the test threshold (10.64)
// exceeds their value range; NaN came from junk LDS -> Inf acc ->
// Inf - Inf in softmax. Now each thread stages 4x float4.
//
// R1 note: importance/load reduction is a deterministic two-pass through
// d_ws (per-block partials, transposed [E][NBLK]) — no atomics anywhere.

#define D_MODEL 2048
#define N_EXP   64
#define BK      64
#define TM      8
#define WAVES   4
#define ROWS_PER_BLOCK (WAVES * TM)
#define NBLK    1024                    // 32768 / ROWS_PER_BLOCK

__global__ __launch_bounds__(256) void router_kernel(
    const float* __restrict__ x, const float* __restrict__ W,
    const float* __restrict__ b,
    float* __restrict__ out_mask, float* __restrict__ out_prob,
    float* __restrict__ pws) {

    __shared__ float Wlds[BK * N_EXP];   // 16 KB
    __shared__ float sums[WAVES][N_EXP]; // 1 KB

    const int tid  = threadIdx.x;
    const int lane = tid & 63;
    // force wave-uniform (scalar) row indexing so x loads become s_load
    const int wv   = __builtin_amdgcn_readfirstlane(tid >> 6);
    const int row0 = blockIdx.x * ROWS_PER_BLOCK + wv * TM;

    const float* xb[TM];
#pragma unroll
    for (int r = 0; r < TM; ++r)
        xb[r] = x + (size_t)(row0 + r) * D_MODEL;

    float acc[TM];
#pragma unroll
    for (int r = 0; r < TM; ++r) acc[r] = 0.0f;

    for (int k0 = 0; k0 < D_MODEL; k0 += BK) {
        // stage the FULL 16KB chunk of W: rows k0..k0+63, all 64 experts.
        // 4096 floats = 1024 float4 = 256 threads x 4.
        const float4* wsrc = (const float4*)(W + (size_t)k0 * N_EXP);
        float4 wchunk[4];
#pragma unroll
        for (int j = 0; j < 4; ++j)
            wchunk[j] = wsrc[tid + 256 * j];
        __syncthreads();                 // previous chunk's readers done
#pragma unroll
        for (int j = 0; j < 4; ++j)
            ((float4*)Wlds)[tid + 256 * j] = wchunk[j];
        __syncthreads();

#pragma unroll 8
        for (int kk = 0; kk < BK; ++kk) {
            float w = Wlds[kk * N_EXP + lane];   // lanes consecutive: 2-way alias, free
#pragma unroll
            for (int r = 0; r < TM; ++r)
                acc[r] = fmaf(xb[r][k0 + kk], w, acc[r]);  // s_load x * v w
        }
    }

    const float bias = b[lane];
    float psum = 0.0f;
    const size_t obase = (size_t)row0 * N_EXP + lane;

#pragma unroll
    for (int r = 0; r < TM; ++r) {
        const float logit = acc[r] + bias;

        // ---- top-1 (value, lowest-index tie-break) ----
        float x1 = logit; int i1 = lane;
#pragma unroll
        for (int m = 32; m > 0; m >>= 1) {
            float ov = __shfl_xor(x1, m);
            int   oi = __shfl_xor(i1, m);
            if (ov > x1 || (ov == x1 && oi < i1)) { x1 = ov; i1 = oi; }
        }
        // ---- top-2 ----
        float v2 = (lane == i1) ? -INFINITY : logit;
        float x2 = v2; int i2 = lane;
#pragma unroll
        for (int m = 32; m > 0; m >>= 1) {
            float ov = __shfl_xor(x2, m);
            int   oi = __shfl_xor(i2, m);
            if (ov > x2 || (ov == x2 && oi < i2)) { x2 = ov; i2 = oi; }
        }
        // ---- top-3 ----
        float v3 = (lane == i1 || lane == i2) ? -INFINITY : logit;
        float x3 = v3; int i3 = lane;
#pragma unroll
        for (int m = 32; m > 0; m >>= 1) {
            float ov = __shfl_xor(x3, m);
            int   oi = __shfl_xor(i3, m);
            if (ov > x3 || (ov == x3 && oi < i3)) { x3 = ov; i3 = oi; }
        }

        // ---- softmax (max = x1) ----
        float e = __expf(logit - x1);
        float s = e;
#pragma unroll
        for (int m = 32; m > 0; m >>= 1) s += __shfl_xor(s, m);
        const float p = e / s;

        out_mask[obase + (size_t)r * N_EXP] =
            (lane == i1 || lane == i2 || lane == i3) ? 1.0f : 0.0f;
        out_prob[obase + (size_t)r * N_EXP] = p;
        psum += p;
    }

    // ---- deterministic cross-wave combine, one partial vector per block ----
    sums[wv][lane] = psum;
    __syncthreads();
    if (tid < N_EXP) {
        const float t = sums[0][tid] + sums[1][tid] + sums[2][tid] + sums[3][tid];
        pws[(size_t)tid * NBLK + blockIdx.x] = t;   // transposed: [E][NBLK]
    }
}

// one block per expert: sum its NBLK contiguous partials -> imp[e], load[e]
__global__ __launch_bounds__(256) void reduce_kernel(
    const float* __restrict__ pws,
    float* __restrict__ out_imp, float* __restrict__ out_load) {

    __shared__ float red[WAVES];
    const int e   = blockIdx.x;
    const int tid = threadIdx.x;

    const float* p = pws + (size_t)e * NBLK;
    float s = p[tid] + p[tid + 256] + p[tid + 512] + p[tid + 768];

#pragma unroll
    for (int m = 32; m > 0; m >>= 1) s += __shfl_xor(s, m);
    if ((tid & 63) == 0) red[tid >> 6] = s;
    __syncthreads();
    if (tid == 0) {
        const float t = red[0] + red[1] + red[2] + red[3];
        out_imp[e]  = t;
        out_load[e] = t;
    }
}

extern "C" void kernel_launch(void* const* d_in, const int* in_sizes, int n_in,
                              void* d_out, int out_size, void* d_ws, size_t ws_size,
                              hipStream_t stream) {
    const float* x = (const float*)d_in[0];
    const float* W = (const float*)d_in[1];
    const float* b = (const float*)d_in[2];

    const int N = in_sizes[0] / D_MODEL;   // 32768

    float* o        = (float*)d_out;
    float* out_mask = o;
    float* out_prob = o + (size_t)N * N_EXP;
    float* out_imp  = out_prob + (size_t)N * N_EXP;
    float* out_load = out_imp + N_EXP;

    float* pws = (float*)d_ws;             // N_EXP * NBLK floats = 256 KB

    router_kernel<<<N / ROWS_PER_BLOCK, 256, 0, stream>>>(
        x, W, b, out_mask, out_prob, pws);
    reduce_kernel<<<N_EXP, 256, 0, stream>>>(pws, out_imp, out_load);
}

// Round 4
// 522.651 us; speedup vs baseline: 1.5052x; 1.5052x over previous
//
#include <hip/hip_runtime.h>
#include <hip/hip_bf16.h>

// MoE Router (Switch): logits = x@W + b; top-3 one-hot mask; softmax probs;
// importance = load = column-sum of probs.
// x: [N=32768, D=2048] f32, W: [D, E=64] f32, b: [E] f32.
// out = [mask (N*E) | prob (N*E) | importance (E) | load (E)]  (f32)
//
// R4 redesign (R3 post-mortem: streaming x through SGPRs overflowed the
// SGPR file -> scratch spills -> 444 MB HBM writes, VALUBusy 13.8%):
//   gemm_kernel: lane = row (64 rows/wave), wave = 16 experts, acc[16] VGPRs.
//     x staged coalesced -> LDS (64 x 68 padded), read per-lane ds_read_b128.
//     W is the wave-uniform operand: 16 floats/k via SMEM (s_load), only
//     ~16-32 SGPRs live. FMA issue density ~93%.
//     Split-K x2 across blocks (4 waves/SIMD); fp32 partials in d_ws
//     (falls back to no split if ws_size too small).
//   epilogue_kernel: lane = expert, wave = 8 rows — the R3-VERIFIED
//     top-k/softmax/mask/prob code, fed by summed partials + bias.
//   reduce_kernel: deterministic two-pass importance/load (R1, verified).

#define D_MODEL 2048
#define N_EXP   64
#define BK      64
#define XPITCH  68            // pad 64 -> 68 words: 16B-aligned, bank-uniform
#define TM      8
#define WAVES   4
#define EROWS   (WAVES * TM)  // 32 rows per epilogue block
#define NBLK    1024          // 32768 / EROWS

// ---------------- GEMM: partial logits pl[row][sp][e] ----------------
__global__ __launch_bounds__(256) void gemm_kernel(
    const float* __restrict__ x, const float* __restrict__ W,
    float* __restrict__ pl, int nsplit) {

    __shared__ float Xlds[64 * XPITCH];   // 17408 B

    const int tid  = threadIdx.x;
    const int lane = tid & 63;
    const int wv   = __builtin_amdgcn_readfirstlane(tid >> 6);
    const int e0   = wv * 16;
    const int rg   = blockIdx.x;          // row group: rows rg*64 .. +63
    const int sp   = blockIdx.y;          // K-split index
    const int dspl = D_MODEL / nsplit;
    const int kbase = sp * dspl;

    float acc[16];
#pragma unroll
    for (int e = 0; e < 16; ++e) acc[e] = 0.0f;

    // staging map: li = j*256+tid; row = li>>4, kk4 = li&15 (16 float4 per row)
    const int srow = tid >> 4;            // base row for j=0 (li<256 -> row<16)
    const int skk4 = tid & 15;

    for (int c = 0; c < dspl; c += BK) {
        float4 tmp[4];
#pragma unroll
        for (int j = 0; j < 4; ++j) {
            const int row = srow + j * 16;
            tmp[j] = *(const float4*)(x + (size_t)(rg * 64 + row) * D_MODEL
                                        + kbase + c + skk4 * 4);
        }
        __syncthreads();                  // prev chunk fully consumed
#pragma unroll
        for (int j = 0; j < 4; ++j) {
            const int row = srow + j * 16;
            *(float4*)&Xlds[row * XPITCH + skk4 * 4] = tmp[j];
        }
        __syncthreads();

#pragma unroll 4
        for (int kk4 = 0; kk4 < BK / 4; ++kk4) {
            const float4 xv = *(const float4*)&Xlds[lane * XPITCH + kk4 * 4];
            const float* wp = W + (size_t)(kbase + c + kk4 * 4) * N_EXP + e0;
#pragma unroll
            for (int j = 0; j < 4; ++j) {
                const float xs = ((const float*)&xv)[j];
#pragma unroll
                for (int e = 0; e < 16; ++e)
                    acc[e] = fmaf(xs, wp[j * N_EXP + e], acc[e]);  // s_load W
            }
        }
    }

    // pl[row][sp][e]: 64 B contiguous per (row,sp,wave)
    float* dst = pl + ((size_t)(rg * 64 + lane) * nsplit + sp) * N_EXP + e0;
#pragma unroll
    for (int e4 = 0; e4 < 4; ++e4)
        *(float4*)(dst + e4 * 4) = *(const float4*)&acc[e4 * 4];
}

// ---------------- epilogue: logits -> topk/softmax/mask/prob ----------------
__global__ __launch_bounds__(256) void epilogue_kernel(
    const float* __restrict__ pl, const float* __restrict__ b,
    float* __restrict__ out_mask, float* __restrict__ out_prob,
    float* __restrict__ pws, int nsplit) {

    __shared__ float sums[WAVES][N_EXP];

    const int tid  = threadIdx.x;
    const int lane = tid & 63;
    const int wv   = tid >> 6;
    const int row0 = blockIdx.x * EROWS + wv * TM;

    const float bias = b[lane];
    float psum = 0.0f;
    const size_t obase = (size_t)row0 * N_EXP + lane;

#pragma unroll
    for (int r = 0; r < TM; ++r) {
        const float* p = pl + (size_t)(row0 + r) * nsplit * N_EXP + lane;
        float logit = bias;
        for (int sp = 0; sp < nsplit; ++sp)
            logit += p[sp * N_EXP];

        // ---- top-1 (value, lowest-index tie-break) ---- [R3-verified]
        float x1 = logit; int i1 = lane;
#pragma unroll
        for (int m = 32; m > 0; m >>= 1) {
            float ov = __shfl_xor(x1, m);
            int   oi = __shfl_xor(i1, m);
            if (ov > x1 || (ov == x1 && oi < i1)) { x1 = ov; i1 = oi; }
        }
        // ---- top-2 ----
        float v2 = (lane == i1) ? -INFINITY : logit;
        float x2 = v2; int i2 = lane;
#pragma unroll
        for (int m = 32; m > 0; m >>= 1) {
            float ov = __shfl_xor(x2, m);
            int   oi = __shfl_xor(i2, m);
            if (ov > x2 || (ov == x2 && oi < i2)) { x2 = ov; i2 = oi; }
        }
        // ---- top-3 ----
        float v3 = (lane == i1 || lane == i2) ? -INFINITY : logit;
        float x3 = v3; int i3 = lane;
#pragma unroll
        for (int m = 32; m > 0; m >>= 1) {
            float ov = __shfl_xor(x3, m);
            int   oi = __shfl_xor(i3, m);
            if (ov > x3 || (ov == x3 && oi < i3)) { x3 = ov; i3 = oi; }
        }

        // ---- softmax (max = x1) ----
        float e = __expf(logit - x1);
        float s = e;
#pragma unroll
        for (int m = 32; m > 0; m >>= 1) s += __shfl_xor(s, m);
        const float p1 = e / s;

        out_mask[obase + (size_t)r * N_EXP] =
            (lane == i1 || lane == i2 || lane == i3) ? 1.0f : 0.0f;
        out_prob[obase + (size_t)r * N_EXP] = p1;
        psum += p1;
    }

    // deterministic cross-wave combine -> one partial vector per block
    sums[wv][lane] = psum;
    __syncthreads();
    if (tid < N_EXP) {
        const float t = sums[0][tid] + sums[1][tid] + sums[2][tid] + sums[3][tid];
        pws[(size_t)tid * NBLK + blockIdx.x] = t;   // transposed: [E][NBLK]
    }
}

// one block per expert: sum its NBLK contiguous partials -> imp[e], load[e]
__global__ __launch_bounds__(256) void reduce_kernel(
    const float* __restrict__ pws,
    float* __restrict__ out_imp, float* __restrict__ out_load) {

    __shared__ float red[WAVES];
    const int e   = blockIdx.x;
    const int tid = threadIdx.x;

    const float* p = pws + (size_t)e * NBLK;
    float s = p[tid] + p[tid + 256] + p[tid + 512] + p[tid + 768];

#pragma unroll
    for (int m = 32; m > 0; m >>= 1) s += __shfl_xor(s, m);
    if ((tid & 63) == 0) red[tid >> 6] = s;
    __syncthreads();
    if (tid == 0) {
        const float t = red[0] + red[1] + red[2] + red[3];
        out_imp[e]  = t;
        out_load[e] = t;
    }
}

extern "C" void kernel_launch(void* const* d_in, const int* in_sizes, int n_in,
                              void* d_out, int out_size, void* d_ws, size_t ws_size,
                              hipStream_t stream) {
    const float* x = (const float*)d_in[0];
    const float* W = (const float*)d_in[1];
    const float* b = (const float*)d_in[2];

    const int N = in_sizes[0] / D_MODEL;   // 32768

    float* o        = (float*)d_out;
    float* out_mask = o;
    float* out_prob = o + (size_t)N * N_EXP;
    float* out_imp  = out_prob + (size_t)N * N_EXP;
    float* out_load = out_imp + N_EXP;

    // workspace: pl (partial logits) + pws (importance partials)
    const size_t need2 = (size_t)N * 2 * N_EXP * 4 + (size_t)N_EXP * NBLK * 4;
    const int nsplit = (ws_size >= need2) ? 2 : 1;   // ws_size constant -> same work every call

    float* pl  = (float*)d_ws;                               // N*nsplit*64 floats
    float* pws = pl + (size_t)N * nsplit * N_EXP;            // 64*1024 floats

    dim3 ggrid(N / 64, nsplit);
    gemm_kernel<<<ggrid, 256, 0, stream>>>(x, W, pl, nsplit);
    epilogue_kernel<<<N / EROWS, 256, 0, stream>>>(pl, b, out_mask, out_prob,
                                                   pws, nsplit);
    reduce_kernel<<<N_EXP, 256, 0, stream>>>(pws, out_imp, out_load);
}